// Round 20
// baseline (83.864 us; speedup 1.0000x reference)
//
#include <hip/hip_runtime.h>

// LayerStacks round 20: R17 (best, 57.7us) with TWO tiles per fused asm block.
// R19 lesson: split issue/wait across asm blocks is unsafe (pending-load regs
// can be copied/spilled by the allocator in the window -> garbage). The SAFE
// pattern is loads+vmcnt in ONE block (R16/R17). This round batches 2 tiles
// (32 loads + one vmcnt(0)) per block => exposed latency windows per wave
// halve (4 -> 2). Outputs "=&v" (early-clobber, R19's correct constraint).
// VGPR rises to ~160-200 => __launch_bounds__(512,3), 12 waves/CU (R13 proved
// occupancy isn't the binding constraint). Compute math identical to R17.

#define NB 6
#define BT 512
#define NW (BT / 64)
#define TILES (BT / 16)     // 32 tiles per block; pairs (w,w+8),(w+16,w+24)

typedef _Float16 h2 __attribute__((ext_vector_type(2)));
typedef _Float16 h8 __attribute__((ext_vector_type(8)));
typedef float f4 __attribute__((ext_vector_type(4)));
typedef unsigned u4v __attribute__((ext_vector_type(4)));

__device__ __forceinline__ h2 pk2(float x, float y) {
    return __builtin_bit_cast(h2, __builtin_amdgcn_cvt_pkrtz(x, y));
}

__device__ __forceinline__ h8 pack8(const float4 a, const float4 b) {
    h2 p0 = pk2(a.x, a.y), p1 = pk2(a.z, a.w);
    h2 p2 = pk2(b.x, b.y), p3 = pk2(b.z, b.w);
    h8 r;
    r[0] = p0[0]; r[1] = p0[1]; r[2] = p1[0]; r[3] = p1[1];
    r[4] = p2[0]; r[5] = p2[1]; r[6] = p3[0]; r[7] = p3[1];
    return r;
}

__device__ __forceinline__ h8 mask8(h8 v, unsigned m) {
    u4v u = __builtin_bit_cast(u4v, v);
    u4v mm = {m, m, m, m};
    u &= mm;
    return __builtin_bit_cast(h8, u);
}

__device__ __forceinline__ float actv(float v) {
    float u = fminf(fmaxf(v, 0.0f), 1.0f);
    return u * u * (255.0f / 256.0f);
}

__global__ __launch_bounds__(BT, 3)
void layerstacks_mfma(const float* __restrict__ x_base,
                      const float* __restrict__ x_pa,
                      const float* __restrict__ mobility,
                      const int*   __restrict__ ply,
                      const float* __restrict__ W1b,
                      const float* __restrict__ b1b,
                      const float* __restrict__ W1pa,
                      const float* __restrict__ b1pa,
                      const float* __restrict__ W2,
                      const float* __restrict__ b2,
                      const float* __restrict__ Wout,
                      const float* __restrict__ bout,
                      float* __restrict__ out)
{
    __shared__ __align__(16) _Float16 sW1[NB][2][4][4][9][8];   // 27.6 KB
    __shared__ __align__(16) _Float16 sW2[NB][4][4][16][8];     // 24.6 KB
    __shared__ float sWo0[NB][64];
    __shared__ float sB2[NB][64];
    __shared__ float sB1[NB][4][8];
    __shared__ float sBout[NB];
    __shared__ float sMob[BT];
    __shared__ int   sBkt[BT];
    __shared__ __align__(16) char sL1[NW * 1280];

    const int tid   = threadIdx.x;
    const int lane  = tid & 63;
    const int w     = tid >> 6;
    const int gbase = blockIdx.x * BT;

    // ---------------- phase 0: staging --------------------------------------
    for (int e = tid; e < NB * 2 * 4 * 4 * 9 * 8; e += BT) {
        int i = e & 7;
        int rest = e >> 3;
        int n = rest % 9;   rest /= 9;
        int kb = rest & 3;  rest >>= 2;
        int t = rest & 3;   rest >>= 2;
        int st = rest & 1;
        int b = rest >> 1;
        int k = t * 32 + kb * 8 + i;
        float v;
        if (n < 8) {
            const float* Wx = st ? W1pa : W1b;
            v = Wx[b * 1032 + n * 129 + k];
        } else {
            v = st ? Wout[b * 320 + 192 + k] : Wout[b * 320 + 64 + k];
        }
        sW1[b][st][t][kb][n][i] = (_Float16)v;
    }
    for (int e = tid; e < NB * 4 * 4 * 16 * 8; e += BT) {
        int i = e & 7;
        int j = (e >> 3) & 15;
        int kb = (e >> 7) & 3;
        int T = (e >> 9) & 3;
        int b = e >> 11;
        int n = T * 16 + j;
        int k = kb * 8 + i;
        int u = k >> 1;
        int colw = (k & 1) ? (16 + u) : u;
        sW2[b][T][kb][j][i] = (_Float16)W2[b * 2048 + n * 32 + colw];
    }
    for (int e = tid; e < NB * 64; e += BT) {
        int b = e >> 6, n = e & 63;
        sWo0[b][n] = Wout[b * 320 + n];
        sB2[b][n]  = b2[e];
    }
    if (tid < NB * 4 * 8) {
        int n = tid & 7, which = (tid >> 3) & 3, b = tid >> 5;
        float v;
        if (which == 0)      v = b1b[b * 8 + n];
        else if (which == 1) v = b1pa[b * 8 + n];
        else if (which == 2) v = W1b [b * 1032 + n * 129 + 128];
        else                 v = W1pa[b * 1032 + n * 129 + 128];
        sB1[b][which][n] = v;
    }
    if (tid < NB) sBout[tid] = bout[tid];
    sMob[tid] = fminf(mobility[gbase + tid] * (7.0f / 255.0f), 1.0f);
    sBkt[tid] = ply[gbase + tid] / 10;
    __syncthreads();

    // ---------------- main ---------------------------------------------------
    const int col = lane & 15;
    const int qd  = lane >> 4;
    char* lb = sL1 + w * 1280;

// full per-tile compute, identical math to R17
#define COMPUTE(TL, X0, X1, X2, X3, X4, X5, X6, X7,                            \
                    Y0, Y1, Y2, Y3, Y4, Y5, Y6, Y7) do {                       \
    const h8 xa0 = pack8(X0, X1), xa1 = pack8(X2, X3);                         \
    const h8 xa2 = pack8(X4, X5), xa3 = pack8(X6, X7);                         \
    const h8 xp0 = pack8(Y0, Y1), xp1 = pack8(Y2, Y3);                         \
    const h8 xp2 = pack8(Y4, Y5), xp3 = pack8(Y6, Y7);                         \
    const int t16 = (TL) << 4;                                                 \
    const int r0 = t16 + qd * 4;                                               \
    const int bbA = sBkt[t16 + col];                                           \
    const int bk0 = sBkt[r0 + 0], bk1 = sBkt[r0 + 1];                          \
    const int bk2 = sBkt[r0 + 2], bk3 = sBkt[r0 + 3];                          \
    const float m0 = sMob[r0 + 0], m1 = sMob[r0 + 1];                          \
    const float m2 = sMob[r0 + 2], m3 = sMob[r0 + 3];                          \
    const int c7 = col & 7;                                                    \
    const bool a8 = (col < 8);                                                 \
    const int ncl = a8 ? col : 8;                                              \
    f4 cb, cp;                                                                 \
    cb[0] = a8 ? sB1[bk0][0][c7] + sB1[bk0][2][c7] * m0 : 0.0f;                \
    cb[1] = a8 ? sB1[bk1][0][c7] + sB1[bk1][2][c7] * m1 : 0.0f;                \
    cb[2] = a8 ? sB1[bk2][0][c7] + sB1[bk2][2][c7] * m2 : 0.0f;                \
    cb[3] = a8 ? sB1[bk3][0][c7] + sB1[bk3][2][c7] * m3 : 0.0f;                \
    cp[0] = a8 ? sB1[bk0][1][c7] + sB1[bk0][3][c7] * m0 : 0.0f;                \
    cp[1] = a8 ? sB1[bk1][1][c7] + sB1[bk1][3][c7] * m1 : 0.0f;                \
    cp[2] = a8 ? sB1[bk2][1][c7] + sB1[bk2][3][c7] * m2 : 0.0f;                \
    cp[3] = a8 ? sB1[bk3][1][c7] + sB1[bk3][3][c7] * m3 : 0.0f;                \
    _Pragma("unroll")                                                          \
    for (int b = 0; b < NB; ++b) {                                             \
        if (!__any(bbA == b)) continue;                                        \
        const unsigned mA = (bbA == b) ? 0xFFFFFFFFu : 0u;                     \
        cb = __builtin_amdgcn_mfma_f32_16x16x32_f16(mask8(xa0, mA), *(const h8*)&sW1[b][0][0][qd][ncl][0], cb, 0, 0, 0); \
        cp = __builtin_amdgcn_mfma_f32_16x16x32_f16(mask8(xp0, mA), *(const h8*)&sW1[b][1][0][qd][ncl][0], cp, 0, 0, 0); \
        cb = __builtin_amdgcn_mfma_f32_16x16x32_f16(mask8(xa1, mA), *(const h8*)&sW1[b][0][1][qd][ncl][0], cb, 0, 0, 0); \
        cp = __builtin_amdgcn_mfma_f32_16x16x32_f16(mask8(xp1, mA), *(const h8*)&sW1[b][1][1][qd][ncl][0], cp, 0, 0, 0); \
        cb = __builtin_amdgcn_mfma_f32_16x16x32_f16(mask8(xa2, mA), *(const h8*)&sW1[b][0][2][qd][ncl][0], cb, 0, 0, 0); \
        cp = __builtin_amdgcn_mfma_f32_16x16x32_f16(mask8(xp2, mA), *(const h8*)&sW1[b][1][2][qd][ncl][0], cp, 0, 0, 0); \
        cb = __builtin_amdgcn_mfma_f32_16x16x32_f16(mask8(xa3, mA), *(const h8*)&sW1[b][0][3][qd][ncl][0], cb, 0, 0, 0); \
        cp = __builtin_amdgcn_mfma_f32_16x16x32_f16(mask8(xp3, mA), *(const h8*)&sW1[b][1][3][qd][ncl][0], cp, 0, 0, 0); \
    }                                                                          \
    if (col < 8) {                                                             \
        _Pragma("unroll")                                                      \
        for (int r = 0; r < 4; ++r) {                                          \
            const int row = qd * 4 + r;                                        \
            float v = cb[r];                                                   \
            *(h2*)(lb + row * 80 + col * 4) =                                  \
                pk2(fminf(v * v * (255.0f / 256.0f), 1.0f),                    \
                    fminf(fmaxf(v, 0.0f), 1.0f));                              \
            v = cp[r];                                                         \
            *(h2*)(lb + row * 80 + 32 + col * 4) =                             \
                pk2(fminf(v * v * (255.0f / 256.0f), 1.0f),                    \
                    fminf(fmaxf(v, 0.0f), 1.0f));                              \
        }                                                                      \
    } else if (col == 8) {                                                     \
        _Pragma("unroll")                                                      \
        for (int r = 0; r < 4; ++r) {                                          \
            const int row = qd * 4 + r;                                        \
            *(float*)(lb + row * 80 + 64) = cb[r];                             \
            *(float*)(lb + row * 80 + 68) = cp[r];                             \
        }                                                                      \
    }                                                                          \
    const h8 a2 = *(const h8*)(lb + col * 80 + qd * 16);                       \
    f4 c20, c21, c22, c23;                                                     \
    c20[0] = sB2[bk0][col];      c20[1] = sB2[bk1][col];                       \
    c20[2] = sB2[bk2][col];      c20[3] = sB2[bk3][col];                       \
    c21[0] = sB2[bk0][16 + col]; c21[1] = sB2[bk1][16 + col];                  \
    c21[2] = sB2[bk2][16 + col]; c21[3] = sB2[bk3][16 + col];                  \
    c22[0] = sB2[bk0][32 + col]; c22[1] = sB2[bk1][32 + col];                  \
    c22[2] = sB2[bk2][32 + col]; c22[3] = sB2[bk3][32 + col];                  \
    c23[0] = sB2[bk0][48 + col]; c23[1] = sB2[bk1][48 + col];                  \
    c23[2] = sB2[bk2][48 + col]; c23[3] = sB2[bk3][48 + col];                  \
    _Pragma("unroll")                                                          \
    for (int b = 0; b < NB; ++b) {                                             \
        if (!__any(bbA == b)) continue;                                        \
        const unsigned mA = (bbA == b) ? 0xFFFFFFFFu : 0u;                     \
        const h8 a2m = mask8(a2, mA);                                          \
        c20 = __builtin_amdgcn_mfma_f32_16x16x32_f16(a2m, *(const h8*)&sW2[b][0][qd][col][0], c20, 0, 0, 0); \
        c21 = __builtin_amdgcn_mfma_f32_16x16x32_f16(a2m, *(const h8*)&sW2[b][1][qd][col][0], c21, 0, 0, 0); \
        c22 = __builtin_amdgcn_mfma_f32_16x16x32_f16(a2m, *(const h8*)&sW2[b][2][qd][col][0], c22, 0, 0, 0); \
        c23 = __builtin_amdgcn_mfma_f32_16x16x32_f16(a2m, *(const h8*)&sW2[b][3][qd][col][0], c23, 0, 0, 0); \
    }                                                                          \
    float p0 = actv(c20[0]) * sWo0[bk0][col]      + actv(c21[0]) * sWo0[bk0][16 + col]  \
             + actv(c22[0]) * sWo0[bk0][32 + col] + actv(c23[0]) * sWo0[bk0][48 + col]; \
    float p1 = actv(c20[1]) * sWo0[bk1][col]      + actv(c21[1]) * sWo0[bk1][16 + col]  \
             + actv(c22[1]) * sWo0[bk1][32 + col] + actv(c23[1]) * sWo0[bk1][48 + col]; \
    float p2 = actv(c20[2]) * sWo0[bk2][col]      + actv(c21[2]) * sWo0[bk2][16 + col]  \
             + actv(c22[2]) * sWo0[bk2][32 + col] + actv(c23[2]) * sWo0[bk2][48 + col]; \
    float p3 = actv(c20[3]) * sWo0[bk3][col]      + actv(c21[3]) * sWo0[bk3][16 + col]  \
             + actv(c22[3]) * sWo0[bk3][32 + col] + actv(c23[3]) * sWo0[bk3][48 + col]; \
    _Pragma("unroll")                                                          \
    for (int m = 1; m < 16; m <<= 1) {                                         \
        p0 += __shfl_xor(p0, m, 64);                                           \
        p1 += __shfl_xor(p1, m, 64);                                           \
        p2 += __shfl_xor(p2, m, 64);                                           \
        p3 += __shfl_xor(p3, m, 64);                                           \
    }                                                                          \
    if (col == 0) {                                                            \
        out[gbase + r0 + 0] = sBout[bk0]                                       \
            + *(const float*)(lb + (qd * 4 + 0) * 80 + 64)                     \
            + *(const float*)(lb + (qd * 4 + 0) * 80 + 68) + p0;               \
        out[gbase + r0 + 1] = sBout[bk1]                                       \
            + *(const float*)(lb + (qd * 4 + 1) * 80 + 64)                     \
            + *(const float*)(lb + (qd * 4 + 1) * 80 + 68) + p1;               \
        out[gbase + r0 + 2] = sBout[bk2]                                       \
            + *(const float*)(lb + (qd * 4 + 2) * 80 + 64)                     \
            + *(const float*)(lb + (qd * 4 + 2) * 80 + 68) + p2;               \
        out[gbase + r0 + 3] = sBout[bk3]                                       \
            + *(const float*)(lb + (qd * 4 + 3) * 80 + 64)                     \
            + *(const float*)(lb + (qd * 4 + 3) * 80 + 68) + p3;               \
    }                                                                          \
} while (0)

    for (int tl = w; tl < TILES; tl += 2 * NW) {
        const float* xbA = x_base + (size_t)(gbase + (tl << 4) + col) * 128 + qd * 8;
        const float* xpA = x_pa   + (size_t)(gbase + (tl << 4) + col) * 128 + qd * 8;
        const float* xbB = x_base + (size_t)(gbase + ((tl + NW) << 4) + col) * 128 + qd * 8;
        const float* xpB = x_pa   + (size_t)(gbase + ((tl + NW) << 4) + col) * 128 + qd * 8;

        float4 a0, a1, a2v, a3, a4, a5, a6, a7;         // tile A x_base
        float4 e0, e1, e2, e3, e4, e5, e6, e7;          // tile A x_pa
        float4 g0, g1, g2, g3, g4, g5, g6, g7;          // tile B x_base
        float4 k0, k1, k2, k3, k4, k5, k6, k7;          // tile B x_pa
        asm volatile(
            "global_load_dwordx4 %0,  %[ab], off\n\t"
            "global_load_dwordx4 %1,  %[ab], off offset:16\n\t"
            "global_load_dwordx4 %2,  %[ab], off offset:128\n\t"
            "global_load_dwordx4 %3,  %[ab], off offset:144\n\t"
            "global_load_dwordx4 %4,  %[ab], off offset:256\n\t"
            "global_load_dwordx4 %5,  %[ab], off offset:272\n\t"
            "global_load_dwordx4 %6,  %[ab], off offset:384\n\t"
            "global_load_dwordx4 %7,  %[ab], off offset:400\n\t"
            "global_load_dwordx4 %8,  %[ap], off\n\t"
            "global_load_dwordx4 %9,  %[ap], off offset:16\n\t"
            "global_load_dwordx4 %10, %[ap], off offset:128\n\t"
            "global_load_dwordx4 %11, %[ap], off offset:144\n\t"
            "global_load_dwordx4 %12, %[ap], off offset:256\n\t"
            "global_load_dwordx4 %13, %[ap], off offset:272\n\t"
            "global_load_dwordx4 %14, %[ap], off offset:384\n\t"
            "global_load_dwordx4 %15, %[ap], off offset:400\n\t"
            "global_load_dwordx4 %16, %[bb], off\n\t"
            "global_load_dwordx4 %17, %[bb], off offset:16\n\t"
            "global_load_dwordx4 %18, %[bb], off offset:128\n\t"
            "global_load_dwordx4 %19, %[bb], off offset:144\n\t"
            "global_load_dwordx4 %20, %[bb], off offset:256\n\t"
            "global_load_dwordx4 %21, %[bb], off offset:272\n\t"
            "global_load_dwordx4 %22, %[bb], off offset:384\n\t"
            "global_load_dwordx4 %23, %[bb], off offset:400\n\t"
            "global_load_dwordx4 %24, %[bp], off\n\t"
            "global_load_dwordx4 %25, %[bp], off offset:16\n\t"
            "global_load_dwordx4 %26, %[bp], off offset:128\n\t"
            "global_load_dwordx4 %27, %[bp], off offset:144\n\t"
            "global_load_dwordx4 %28, %[bp], off offset:256\n\t"
            "global_load_dwordx4 %29, %[bp], off offset:272\n\t"
            "global_load_dwordx4 %30, %[bp], off offset:384\n\t"
            "global_load_dwordx4 %31, %[bp], off offset:400\n\t"
            "s_waitcnt vmcnt(0)"
            : "=&v"(a0), "=&v"(a1), "=&v"(a2v), "=&v"(a3),
              "=&v"(a4), "=&v"(a5), "=&v"(a6),  "=&v"(a7),
              "=&v"(e0), "=&v"(e1), "=&v"(e2),  "=&v"(e3),
              "=&v"(e4), "=&v"(e5), "=&v"(e6),  "=&v"(e7),
              "=&v"(g0), "=&v"(g1), "=&v"(g2),  "=&v"(g3),
              "=&v"(g4), "=&v"(g5), "=&v"(g6),  "=&v"(g7),
              "=&v"(k0), "=&v"(k1), "=&v"(k2),  "=&v"(k3),
              "=&v"(k4), "=&v"(k5), "=&v"(k6),  "=&v"(k7)
            : [ab] "v"(xbA), [ap] "v"(xpA), [bb] "v"(xbB), [bp] "v"(xpB)
            : "memory");

        COMPUTE(tl,      a0, a1, a2v, a3, a4, a5, a6, a7,
                         e0, e1, e2,  e3, e4, e5, e6, e7);
        COMPUTE(tl + NW, g0, g1, g2,  g3, g4, g5, g6, g7,
                         k0, k1, k2,  k3, k4, k5, k6, k7);
    }
#undef COMPUTE
}

extern "C" void kernel_launch(void* const* d_in, const int* in_sizes, int n_in,
                              void* d_out, int out_size, void* d_ws, size_t ws_size,
                              hipStream_t stream) {
    const float* x_base   = (const float*)d_in[0];
    const float* x_pa     = (const float*)d_in[1];
    const float* mobility = (const float*)d_in[2];
    const int*   ply      = (const int*)d_in[3];
    const float* W1b      = (const float*)d_in[4];
    const float* b1b      = (const float*)d_in[5];
    const float* W1pa     = (const float*)d_in[6];
    const float* b1pa     = (const float*)d_in[7];
    const float* W2       = (const float*)d_in[8];
    const float* b2       = (const float*)d_in[9];
    const float* Wout     = (const float*)d_in[10];
    const float* bout     = (const float*)d_in[11];
    float* out = (float*)d_out;

    const int B = in_sizes[3];              // 262144 (multiple of 512)
    const int blocks = B / BT;              // 512
    layerstacks_mfma<<<blocks, BT, 0, stream>>>(
        x_base, x_pa, mobility, ply, W1b, b1b, W1pa, b1pa, W2, b2, Wout, bout, out);
}

// Round 21
// 58.189 us; speedup vs baseline: 1.4412x; 1.4412x over previous
//
#include <hip/hip_runtime.h>

// LayerStacks round 21: R17 (best, 57.7us) with PLAIN compiler loads.
// Final unexplored cell of the lever matrix: {plain loads x natural order}.
// R17's opaque asm (16 loads + fused vmcnt(0)) forbids ALL load/compute
// overlap; with natural-order affine addresses the compiler may pipeline
// better on its own (its conservative sinking was only proven harmful on the
// permuted gather, R8/R9). Everything else byte-identical to R17.
// A/B read: <=57.7 -> asm was neutral/hurting; if null, R17 ~= the L3-BW
// roofline for this access shape (4.6 TB/s demand, 74% of copy ceiling).

#define NB 6
#define BT 512
#define NW (BT / 64)
#define TILES (BT / 16)     // 32 tiles per block

typedef _Float16 h2 __attribute__((ext_vector_type(2)));
typedef _Float16 h8 __attribute__((ext_vector_type(8)));
typedef float f4 __attribute__((ext_vector_type(4)));
typedef unsigned u4v __attribute__((ext_vector_type(4)));

__device__ __forceinline__ h2 pk2(float x, float y) {
    return __builtin_bit_cast(h2, __builtin_amdgcn_cvt_pkrtz(x, y));
}

__device__ __forceinline__ h8 pack8(const float4 a, const float4 b) {
    h2 p0 = pk2(a.x, a.y), p1 = pk2(a.z, a.w);
    h2 p2 = pk2(b.x, b.y), p3 = pk2(b.z, b.w);
    h8 r;
    r[0] = p0[0]; r[1] = p0[1]; r[2] = p1[0]; r[3] = p1[1];
    r[4] = p2[0]; r[5] = p2[1]; r[6] = p3[0]; r[7] = p3[1];
    return r;
}

__device__ __forceinline__ h8 mask8(h8 v, unsigned m) {
    u4v u = __builtin_bit_cast(u4v, v);
    u4v mm = {m, m, m, m};
    u &= mm;
    return __builtin_bit_cast(h8, u);
}

__device__ __forceinline__ float actv(float v) {
    float u = fminf(fmaxf(v, 0.0f), 1.0f);
    return u * u * (255.0f / 256.0f);
}

__global__ __launch_bounds__(BT, 4)
void layerstacks_mfma(const float* __restrict__ x_base,
                      const float* __restrict__ x_pa,
                      const float* __restrict__ mobility,
                      const int*   __restrict__ ply,
                      const float* __restrict__ W1b,
                      const float* __restrict__ b1b,
                      const float* __restrict__ W1pa,
                      const float* __restrict__ b1pa,
                      const float* __restrict__ W2,
                      const float* __restrict__ b2,
                      const float* __restrict__ Wout,
                      const float* __restrict__ bout,
                      float* __restrict__ out)
{
    __shared__ __align__(16) _Float16 sW1[NB][2][4][4][9][8];   // 27.6 KB
    __shared__ __align__(16) _Float16 sW2[NB][4][4][16][8];     // 24.6 KB
    __shared__ float sWo0[NB][64];
    __shared__ float sB2[NB][64];
    __shared__ float sB1[NB][4][8];
    __shared__ float sBout[NB];
    __shared__ float sMob[BT];
    __shared__ int   sBkt[BT];
    __shared__ __align__(16) char sL1[NW * 1280];

    const int tid   = threadIdx.x;
    const int lane  = tid & 63;
    const int w     = tid >> 6;
    const int gbase = blockIdx.x * BT;

    // ---------------- phase 0: staging --------------------------------------
    for (int e = tid; e < NB * 2 * 4 * 4 * 9 * 8; e += BT) {
        int i = e & 7;
        int rest = e >> 3;
        int n = rest % 9;   rest /= 9;
        int kb = rest & 3;  rest >>= 2;
        int t = rest & 3;   rest >>= 2;
        int st = rest & 1;
        int b = rest >> 1;
        int k = t * 32 + kb * 8 + i;
        float v;
        if (n < 8) {
            const float* Wx = st ? W1pa : W1b;
            v = Wx[b * 1032 + n * 129 + k];
        } else {
            v = st ? Wout[b * 320 + 192 + k] : Wout[b * 320 + 64 + k];
        }
        sW1[b][st][t][kb][n][i] = (_Float16)v;
    }
    for (int e = tid; e < NB * 4 * 4 * 16 * 8; e += BT) {
        int i = e & 7;
        int j = (e >> 3) & 15;
        int kb = (e >> 7) & 3;
        int T = (e >> 9) & 3;
        int b = e >> 11;
        int n = T * 16 + j;
        int k = kb * 8 + i;
        int u = k >> 1;
        int colw = (k & 1) ? (16 + u) : u;
        sW2[b][T][kb][j][i] = (_Float16)W2[b * 2048 + n * 32 + colw];
    }
    for (int e = tid; e < NB * 64; e += BT) {
        int b = e >> 6, n = e & 63;
        sWo0[b][n] = Wout[b * 320 + n];
        sB2[b][n]  = b2[e];
    }
    if (tid < NB * 4 * 8) {
        int n = tid & 7, which = (tid >> 3) & 3, b = tid >> 5;
        float v;
        if (which == 0)      v = b1b[b * 8 + n];
        else if (which == 1) v = b1pa[b * 8 + n];
        else if (which == 2) v = W1b [b * 1032 + n * 129 + 128];
        else                 v = W1pa[b * 1032 + n * 129 + 128];
        sB1[b][which][n] = v;
    }
    if (tid < NB) sBout[tid] = bout[tid];
    sMob[tid] = fminf(mobility[gbase + tid] * (7.0f / 255.0f), 1.0f);
    sBkt[tid] = ply[gbase + tid] / 10;
    __syncthreads();

    // ---------------- main: natural-order tiles, bucket-masked MFMA ---------
    const int col = lane & 15;
    const int qd  = lane >> 4;
    char* lb = sL1 + w * 1280;

    for (int tl = w; tl < TILES; tl += NW) {
        const int t16 = tl << 4;
        const int r0 = t16 + qd * 4;

        // ---- 16 x loads (consecutive rows), plain compiler loads ----------
        const float* xbrow = x_base + (size_t)(gbase + t16 + col) * 128 + qd * 8;
        const float* xprow = x_pa   + (size_t)(gbase + t16 + col) * 128 + qd * 8;
        const float4 b00 = *(const float4*)(xbrow + 0);
        const float4 b01 = *(const float4*)(xbrow + 4);
        const float4 b10 = *(const float4*)(xbrow + 32);
        const float4 b11 = *(const float4*)(xbrow + 36);
        const float4 b20 = *(const float4*)(xbrow + 64);
        const float4 b21 = *(const float4*)(xbrow + 68);
        const float4 b30 = *(const float4*)(xbrow + 96);
        const float4 b31 = *(const float4*)(xbrow + 100);
        const float4 q00 = *(const float4*)(xprow + 0);
        const float4 q01 = *(const float4*)(xprow + 4);
        const float4 q10 = *(const float4*)(xprow + 32);
        const float4 q11 = *(const float4*)(xprow + 36);
        const float4 q20 = *(const float4*)(xprow + 64);
        const float4 q21 = *(const float4*)(xprow + 68);
        const float4 q30 = *(const float4*)(xprow + 96);
        const float4 q31 = *(const float4*)(xprow + 100);

        // pack once
        const h8 xa0 = pack8(b00, b01), xa1 = pack8(b10, b11);
        const h8 xa2 = pack8(b20, b21), xa3 = pack8(b30, b31);
        const h8 xp0 = pack8(q00, q01), xp1 = pack8(q10, q11);
        const h8 xp2 = pack8(q20, q21), xp3 = pack8(q30, q31);

        const int bbA = sBkt[t16 + col];
        const int bk0 = sBkt[r0 + 0], bk1 = sBkt[r0 + 1];
        const int bk2 = sBkt[r0 + 2], bk3 = sBkt[r0 + 3];
        const float m0 = sMob[r0 + 0], m1 = sMob[r0 + 1];
        const float m2 = sMob[r0 + 2], m3 = sMob[r0 + 3];

        const int c7 = col & 7;
        const bool a8 = (col < 8);
        const int ncl = a8 ? col : 8;

        // ---- stage 1 seeds (per-row bucket) --------------------------------
        f4 cb, cp;
        cb[0] = a8 ? sB1[bk0][0][c7] + sB1[bk0][2][c7] * m0 : 0.0f;
        cb[1] = a8 ? sB1[bk1][0][c7] + sB1[bk1][2][c7] * m1 : 0.0f;
        cb[2] = a8 ? sB1[bk2][0][c7] + sB1[bk2][2][c7] * m2 : 0.0f;
        cb[3] = a8 ? sB1[bk3][0][c7] + sB1[bk3][2][c7] * m3 : 0.0f;
        cp[0] = a8 ? sB1[bk0][1][c7] + sB1[bk0][3][c7] * m0 : 0.0f;
        cp[1] = a8 ? sB1[bk1][1][c7] + sB1[bk1][3][c7] * m1 : 0.0f;
        cp[2] = a8 ? sB1[bk2][1][c7] + sB1[bk2][3][c7] * m2 : 0.0f;
        cp[3] = a8 ? sB1[bk3][1][c7] + sB1[bk3][3][c7] * m3 : 0.0f;

        // ---- stage 1: accumulate over buckets with masked A ----------------
        #pragma unroll
        for (int b = 0; b < NB; ++b) {
            if (!__any(bbA == b)) continue;
            const unsigned mA = (bbA == b) ? 0xFFFFFFFFu : 0u;
            cb = __builtin_amdgcn_mfma_f32_16x16x32_f16(mask8(xa0, mA), *(const h8*)&sW1[b][0][0][qd][ncl][0], cb, 0, 0, 0);
            cp = __builtin_amdgcn_mfma_f32_16x16x32_f16(mask8(xp0, mA), *(const h8*)&sW1[b][1][0][qd][ncl][0], cp, 0, 0, 0);
            cb = __builtin_amdgcn_mfma_f32_16x16x32_f16(mask8(xa1, mA), *(const h8*)&sW1[b][0][1][qd][ncl][0], cb, 0, 0, 0);
            cp = __builtin_amdgcn_mfma_f32_16x16x32_f16(mask8(xp1, mA), *(const h8*)&sW1[b][1][1][qd][ncl][0], cp, 0, 0, 0);
            cb = __builtin_amdgcn_mfma_f32_16x16x32_f16(mask8(xa2, mA), *(const h8*)&sW1[b][0][2][qd][ncl][0], cb, 0, 0, 0);
            cp = __builtin_amdgcn_mfma_f32_16x16x32_f16(mask8(xp2, mA), *(const h8*)&sW1[b][1][2][qd][ncl][0], cp, 0, 0, 0);
            cb = __builtin_amdgcn_mfma_f32_16x16x32_f16(mask8(xa3, mA), *(const h8*)&sW1[b][0][3][qd][ncl][0], cb, 0, 0, 0);
            cp = __builtin_amdgcn_mfma_f32_16x16x32_f16(mask8(xp3, mA), *(const h8*)&sW1[b][1][3][qd][ncl][0], cp, 0, 0, 0);
        }

        // ---- epilogue 1: l1c pairs -> per-wave scratch ---------------------
        if (col < 8) {
            #pragma unroll
            for (int r = 0; r < 4; ++r) {
                const int row = qd * 4 + r;
                float v = cb[r];
                *(h2*)(lb + row * 80 + col * 4) =
                    pk2(fminf(v * v * (255.0f / 256.0f), 1.0f),
                        fminf(fmaxf(v, 0.0f), 1.0f));
                v = cp[r];
                *(h2*)(lb + row * 80 + 32 + col * 4) =
                    pk2(fminf(v * v * (255.0f / 256.0f), 1.0f),
                        fminf(fmaxf(v, 0.0f), 1.0f));
            }
        } else if (col == 8) {
            #pragma unroll
            for (int r = 0; r < 4; ++r) {
                const int row = qd * 4 + r;
                *(float*)(lb + row * 80 + 64) = cb[r];
                *(float*)(lb + row * 80 + 68) = cp[r];
            }
        }

        // ---- stage 2: L2 (K=32), bucket-masked A ---------------------------
        const h8 a2 = *(const h8*)(lb + col * 80 + qd * 16);
        f4 c20, c21, c22, c23;
        c20[0] = sB2[bk0][col];      c20[1] = sB2[bk1][col];
        c20[2] = sB2[bk2][col];      c20[3] = sB2[bk3][col];
        c21[0] = sB2[bk0][16 + col]; c21[1] = sB2[bk1][16 + col];
        c21[2] = sB2[bk2][16 + col]; c21[3] = sB2[bk3][16 + col];
        c22[0] = sB2[bk0][32 + col]; c22[1] = sB2[bk1][32 + col];
        c22[2] = sB2[bk2][32 + col]; c22[3] = sB2[bk3][32 + col];
        c23[0] = sB2[bk0][48 + col]; c23[1] = sB2[bk1][48 + col];
        c23[2] = sB2[bk2][48 + col]; c23[3] = sB2[bk3][48 + col];

        #pragma unroll
        for (int b = 0; b < NB; ++b) {
            if (!__any(bbA == b)) continue;
            const unsigned mA = (bbA == b) ? 0xFFFFFFFFu : 0u;
            const h8 a2m = mask8(a2, mA);
            c20 = __builtin_amdgcn_mfma_f32_16x16x32_f16(a2m, *(const h8*)&sW2[b][0][qd][col][0], c20, 0, 0, 0);
            c21 = __builtin_amdgcn_mfma_f32_16x16x32_f16(a2m, *(const h8*)&sW2[b][1][qd][col][0], c21, 0, 0, 0);
            c22 = __builtin_amdgcn_mfma_f32_16x16x32_f16(a2m, *(const h8*)&sW2[b][2][qd][col][0], c22, 0, 0, 0);
            c23 = __builtin_amdgcn_mfma_f32_16x16x32_f16(a2m, *(const h8*)&sW2[b][3][qd][col][0], c23, 0, 0, 0);
        }

        // ---- epilogue 2: activation + per-row Wout[0:64) dot + reduce ------
        float p0 = actv(c20[0]) * sWo0[bk0][col]      + actv(c21[0]) * sWo0[bk0][16 + col]
                 + actv(c22[0]) * sWo0[bk0][32 + col] + actv(c23[0]) * sWo0[bk0][48 + col];
        float p1 = actv(c20[1]) * sWo0[bk1][col]      + actv(c21[1]) * sWo0[bk1][16 + col]
                 + actv(c22[1]) * sWo0[bk1][32 + col] + actv(c23[1]) * sWo0[bk1][48 + col];
        float p2 = actv(c20[2]) * sWo0[bk2][col]      + actv(c21[2]) * sWo0[bk2][16 + col]
                 + actv(c22[2]) * sWo0[bk2][32 + col] + actv(c23[2]) * sWo0[bk2][48 + col];
        float p3 = actv(c20[3]) * sWo0[bk3][col]      + actv(c21[3]) * sWo0[bk3][16 + col]
                 + actv(c22[3]) * sWo0[bk3][32 + col] + actv(c23[3]) * sWo0[bk3][48 + col];
        #pragma unroll
        for (int m = 1; m < 16; m <<= 1) {
            p0 += __shfl_xor(p0, m, 64);
            p1 += __shfl_xor(p1, m, 64);
            p2 += __shfl_xor(p2, m, 64);
            p3 += __shfl_xor(p3, m, 64);
        }

        if (col == 0) {
            out[gbase + r0 + 0] = sBout[bk0]
                + *(const float*)(lb + (qd * 4 + 0) * 80 + 64)
                + *(const float*)(lb + (qd * 4 + 0) * 80 + 68) + p0;
            out[gbase + r0 + 1] = sBout[bk1]
                + *(const float*)(lb + (qd * 4 + 1) * 80 + 64)
                + *(const float*)(lb + (qd * 4 + 1) * 80 + 68) + p1;
            out[gbase + r0 + 2] = sBout[bk2]
                + *(const float*)(lb + (qd * 4 + 2) * 80 + 64)
                + *(const float*)(lb + (qd * 4 + 2) * 80 + 68) + p2;
            out[gbase + r0 + 3] = sBout[bk3]
                + *(const float*)(lb + (qd * 4 + 3) * 80 + 64)
                + *(const float*)(lb + (qd * 4 + 3) * 80 + 68) + p3;
        }
    }
}

extern "C" void kernel_launch(void* const* d_in, const int* in_sizes, int n_in,
                              void* d_out, int out_size, void* d_ws, size_t ws_size,
                              hipStream_t stream) {
    const float* x_base   = (const float*)d_in[0];
    const float* x_pa     = (const float*)d_in[1];
    const float* mobility = (const float*)d_in[2];
    const int*   ply      = (const int*)d_in[3];
    const float* W1b      = (const float*)d_in[4];
    const float* b1b      = (const float*)d_in[5];
    const float* W1pa     = (const float*)d_in[6];
    const float* b1pa     = (const float*)d_in[7];
    const float* W2       = (const float*)d_in[8];
    const float* b2       = (const float*)d_in[9];
    const float* Wout     = (const float*)d_in[10];
    const float* bout     = (const float*)d_in[11];
    float* out = (float*)d_out;

    const int B = in_sizes[3];              // 262144 (multiple of 512)
    const int blocks = B / BT;              // 512
    layerstacks_mfma<<<blocks, BT, 0, stream>>>(
        x_base, x_pa, mobility, ply, W1b, b1b, W1pa, b1pa, W2, b2, Wout, bout, out);
}